// Round 4
// baseline (409.286 us; speedup 1.0000x reference)
//
#include <hip/hip_runtime.h>

typedef __attribute__((ext_vector_type(8))) short bf16x8;
typedef __attribute__((ext_vector_type(4))) float floatx4;

static __device__ __forceinline__ float b2f(unsigned short u) {
  union { unsigned int i; float f; } v; v.i = ((unsigned int)u) << 16; return v.f;
}
static __device__ __forceinline__ unsigned short f2b(float f) {
  union { float f; unsigned int i; } v; v.f = f;
  unsigned int x = v.i;
  return (unsigned short)((x + 0x7fffu + ((x >> 16) & 1u)) >> 16);
}

// ---------------- fp32 -> bf16 elementwise convert ------------------------------
__global__ void cvt_f32_bf16(const float* __restrict__ src,
                             unsigned short* __restrict__ dst) {
  int i = (blockIdx.x * 256 + threadIdx.x) * 4;
  float4 v = *(const float4*)(src + i);
  ushort4 o;
  o.x = f2b(v.x); o.y = f2b(v.y); o.z = f2b(v.z); o.w = f2b(v.w);
  *(ushort4*)(dst + i) = o;
}

// ------------- weight convert+transpose: fp32 [K,N] -> bf16 [N,K] ---------------
__global__ void transpose_f32_bf16(const float* __restrict__ src,
                                   unsigned short* __restrict__ dst, int K, int N) {
  __shared__ unsigned short tile[32][33];
  src += (size_t)blockIdx.z * K * N;
  dst += (size_t)blockIdx.z * K * N;
  const int bx = blockIdx.x * 32;  // N offset
  const int by = blockIdx.y * 32;  // K offset
  const int tx = threadIdx.x, ty = threadIdx.y;  // 32 x 8
#pragma unroll
  for (int i = 0; i < 4; i++)
    tile[ty + i * 8][tx] = f2b(src[(size_t)(by + ty + i * 8) * N + bx + tx]);
  __syncthreads();
#pragma unroll
  for (int i = 0; i < 4; i++)
    dst[(size_t)(bx + ty + i * 8) * K + by + tx] = tile[tx][ty + i * 8];
}

// ---------------- router: fp32 softmax over 8 logits, zero 2 smallest -----------
__global__ void router_topk(const float* __restrict__ X,
                            const float* __restrict__ RW,
                            float* __restrict__ cw) {
  const int t = blockIdx.x;
  const int lane = threadIdx.x;  // 64
  float acc[8];
#pragma unroll
  for (int e = 0; e < 8; e++) acc[e] = 0.f;
  for (int d = lane; d < 1024; d += 64) {
    float xv = X[(size_t)t * 1024 + d];
    const float* r = RW + d * 8;
    float4 r0 = *(const float4*)r;
    float4 r1 = *(const float4*)(r + 4);
    acc[0] += xv * r0.x; acc[1] += xv * r0.y;
    acc[2] += xv * r0.z; acc[3] += xv * r0.w;
    acc[4] += xv * r1.x; acc[5] += xv * r1.y;
    acc[6] += xv * r1.z; acc[7] += xv * r1.w;
  }
#pragma unroll
  for (int m = 1; m < 64; m <<= 1) {
#pragma unroll
    for (int e = 0; e < 8; e++) acc[e] += __shfl_xor(acc[e], m);
  }
  if (lane == 0) {
    float mx = acc[0];
#pragma unroll
    for (int e = 1; e < 8; e++) mx = fmaxf(mx, acc[e]);
    float prob[8], s = 0.f;
#pragma unroll
    for (int e = 0; e < 8; e++) { prob[e] = expf(acc[e] - mx); s += prob[e]; }
    float inv = 1.f / s;
#pragma unroll
    for (int e = 0; e < 8; e++) prob[e] *= inv;
    int m1 = 0;
#pragma unroll
    for (int e = 1; e < 8; e++) if (prob[e] < prob[m1]) m1 = e;
    int m2 = -1;
#pragma unroll
    for (int e = 0; e < 8; e++)
      if (e != m1 && (m2 < 0 || prob[e] < prob[m2])) m2 = e;
#pragma unroll
    for (int e = 0; e < 8; e++)
      cw[(size_t)t * 8 + e] = (e == m1 || e == m2) ? 0.f : prob[e];
  }
}

// ---------------- GEMM core: 128x128 tile, BK=32, 4 waves (2x2, 64x64 each) -----
// X: bf16 [rows,1024] row-major (k contiguous), pre-offset to chunk start.
// B^T rows: n-major, k contiguous; routed wT [E][512][1024], shared [1024][1024].
// Output column space: [0,4096) routed (expert = n0>>9), [4096,5120) shared.
// GH is chunk-local bf16 [rows][5120]. cw pre-offset to chunk start.
// MODE 0: store raw acc (gate pre-activation G) to GH.
// MODE 1: read G from GH, compute  cw * silu(G) * acc  -> H, in place.
template <int MODE>
__global__ __launch_bounds__(256) void gemm_gu(
    const unsigned short* __restrict__ X,
    const unsigned short* __restrict__ WTe,
    const unsigned short* __restrict__ WTs,
    unsigned short* GH,
    const float* __restrict__ cw) {
  __shared__ __align__(16) unsigned short lA[128 * 32];
  __shared__ __align__(16) unsigned short lB[128 * 32];
  const int tid = threadIdx.x;
  const int wid = tid >> 6, lane = tid & 63;
  const int lr = lane & 15, quad = lane >> 4;
  const int wm = wid >> 1, wn = wid & 1;
  const int m0 = blockIdx.x * 128;
  const int n0 = blockIdx.y * 128;

  const unsigned short* Bbase;
  int eidx = -1;
  if (n0 < 4096) {
    eidx = n0 >> 9;
    Bbase = WTe + ((size_t)eidx * 512 + (n0 & 511)) * 1024;
  } else {
    Bbase = WTs + (size_t)(n0 - 4096) * 1024;
  }

  floatx4 acc[4][4];
#pragma unroll
  for (int i = 0; i < 4; i++)
#pragma unroll
    for (int j = 0; j < 4; j++) acc[i][j] = (floatx4)0.f;

  for (int k0 = 0; k0 < 1024; k0 += 32) {
    bf16x8 av[2], bv[2];
#pragma unroll
    for (int i = 0; i < 2; i++) {
      int c = i * 256 + tid;
      av[i] = *(const bf16x8*)(X + (size_t)(m0 + (c >> 2)) * 1024 + k0 + ((c & 3) << 3));
      bv[i] = *(const bf16x8*)(Bbase + (size_t)(c >> 2) * 1024 + k0 + ((c & 3) << 3));
    }
    __syncthreads();
#pragma unroll
    for (int i = 0; i < 2; i++) {
      int c = i * 256 + tid;
      *(bf16x8*)(lA + (size_t)c * 8) = av[i];
      *(bf16x8*)(lB + (size_t)c * 8) = bv[i];
    }
    __syncthreads();
    bf16x8 af[4], bfr[4];
#pragma unroll
    for (int mt = 0; mt < 4; mt++)
      af[mt] = *(const bf16x8*)(lA + (wm * 64 + mt * 16 + lr) * 32 + quad * 8);
#pragma unroll
    for (int nt = 0; nt < 4; nt++)
      bfr[nt] = *(const bf16x8*)(lB + (wn * 64 + nt * 16 + lr) * 32 + quad * 8);
#pragma unroll
    for (int mt = 0; mt < 4; mt++)
#pragma unroll
      for (int nt = 0; nt < 4; nt++)
        acc[mt][nt] = __builtin_amdgcn_mfma_f32_16x16x32_bf16(
            af[mt], bfr[nt], acc[mt][nt], 0, 0, 0);
  }

#pragma unroll
  for (int mt = 0; mt < 4; mt++) {
#pragma unroll
    for (int nt = 0; nt < 4; nt++) {
#pragma unroll
      for (int r = 0; r < 4; r++) {
        int row = m0 + wm * 64 + mt * 16 + quad * 4 + r;
        int col = n0 + wn * 64 + nt * 16 + lr;
        size_t idx = (size_t)row * 5120 + col;
        if (MODE == 0) {
          GH[idx] = f2b(acc[mt][nt][r]);
        } else {
          float g = b2f(GH[idx]);
          float u = acc[mt][nt][r];
          float s = (eidx >= 0) ? cw[(size_t)row * 8 + eidx] : 1.0f;
          float silu = g / (1.0f + __expf(-g));
          GH[idx] = f2b(s * silu * u);
        }
      }
    }
  }
}

// ---------------- down GEMM: Y[rows,1024] = H[rows,5120] @ Wd_cat (fp32 out) ----
// B^T rows: output col d, k contiguous. routed: wT [E][1024][512] (ldB=512),
// shared: wsT [1024][1024] (ldB=1024). H chunk-local; Y pre-offset, fp32.
__global__ __launch_bounds__(256) void gemm_down(
    const unsigned short* __restrict__ H,
    const unsigned short* __restrict__ WdTe,
    const unsigned short* __restrict__ WdTs,
    float* __restrict__ Y) {
  __shared__ __align__(16) unsigned short lA[128 * 32];
  __shared__ __align__(16) unsigned short lB[128 * 32];
  const int tid = threadIdx.x;
  const int wid = tid >> 6, lane = tid & 63;
  const int lr = lane & 15, quad = lane >> 4;
  const int wm = wid >> 1, wn = wid & 1;
  const int m0 = blockIdx.x * 128;
  const int n0 = blockIdx.y * 128;

  floatx4 acc[4][4];
#pragma unroll
  for (int i = 0; i < 4; i++)
#pragma unroll
    for (int j = 0; j < 4; j++) acc[i][j] = (floatx4)0.f;

  for (int k0 = 0; k0 < 5120; k0 += 32) {
    bf16x8 av[2], bv[2];
#pragma unroll
    for (int i = 0; i < 2; i++) {
      int c = i * 256 + tid;
      av[i] = *(const bf16x8*)(H + (size_t)(m0 + (c >> 2)) * 5120 + k0 + ((c & 3) << 3));
    }
    if (k0 < 4096) {
      int e = k0 >> 9;
#pragma unroll
      for (int i = 0; i < 2; i++) {
        int c = i * 256 + tid;
        bv[i] = *(const bf16x8*)(WdTe + (size_t)e * 1024 * 512 +
                                 (size_t)(n0 + (c >> 2)) * 512 + (k0 & 511) +
                                 ((c & 3) << 3));
      }
    } else {
#pragma unroll
      for (int i = 0; i < 2; i++) {
        int c = i * 256 + tid;
        bv[i] = *(const bf16x8*)(WdTs + (size_t)(n0 + (c >> 2)) * 1024 +
                                 (k0 - 4096) + ((c & 3) << 3));
      }
    }
    __syncthreads();
#pragma unroll
    for (int i = 0; i < 2; i++) {
      int c = i * 256 + tid;
      *(bf16x8*)(lA + (size_t)c * 8) = av[i];
      *(bf16x8*)(lB + (size_t)c * 8) = bv[i];
    }
    __syncthreads();
    bf16x8 af[4], bfr[4];
#pragma unroll
    for (int mt = 0; mt < 4; mt++)
      af[mt] = *(const bf16x8*)(lA + (wm * 64 + mt * 16 + lr) * 32 + quad * 8);
#pragma unroll
    for (int nt = 0; nt < 4; nt++)
      bfr[nt] = *(const bf16x8*)(lB + (wn * 64 + nt * 16 + lr) * 32 + quad * 8);
#pragma unroll
    for (int mt = 0; mt < 4; mt++)
#pragma unroll
      for (int nt = 0; nt < 4; nt++)
        acc[mt][nt] = __builtin_amdgcn_mfma_f32_16x16x32_bf16(
            af[mt], bfr[nt], acc[mt][nt], 0, 0, 0);
  }

#pragma unroll
  for (int mt = 0; mt < 4; mt++)
#pragma unroll
    for (int nt = 0; nt < 4; nt++)
#pragma unroll
      for (int r = 0; r < 4; r++) {
        int row = m0 + wm * 64 + mt * 16 + quad * 4 + r;
        int col = n0 + wn * 64 + nt * 16 + lr;
        Y[(size_t)row * 1024 + col] = acc[mt][nt][r];
      }
}

extern "C" void kernel_launch(void* const* d_in, const int* in_sizes, int n_in,
                              void* d_out, int out_size, void* d_ws, size_t ws_size,
                              hipStream_t stream) {
  const float* hs  = (const float*)d_in[0];
  const float* rw  = (const float*)d_in[1];
  const float* wg  = (const float*)d_in[2];
  const float* wu  = (const float*)d_in[3];
  const float* wd  = (const float*)d_in[4];
  const float* wsg = (const float*)d_in[5];
  const float* wsu = (const float*)d_in[6];
  const float* wsd = (const float*)d_in[7];
  float* out = (float*)d_out;

  // workspace layout:
  //   cw  [4096*8] f32            128 KB
  //   Xb  [4096*1024] bf16          8 MB  (hs converted to bf16)
  //   wT  [8*512*1024] bf16         8 MB  (reused: gateT / upT / downT)
  //   wsT [1024*1024] bf16          2 MB  (reused: shared gateT / upT / downT)
  //   GH  [rows_per_chunk*5120] bf16      (G, then H in place; chunk-local)
  char* p = (char*)d_ws;
  float* cw = (float*)p;                    p += (size_t)4096 * 8 * 4;
  unsigned short* Xb  = (unsigned short*)p; p += (size_t)4096 * 1024 * 2;
  unsigned short* wT  = (unsigned short*)p; p += (size_t)8 * 512 * 1024 * 2;
  unsigned short* wsT = (unsigned short*)p; p += (size_t)1024 * 1024 * 2;
  unsigned short* GH  = (unsigned short*)p;
  const size_t base_bytes = (size_t)(p - (char*)d_ws);

  // Tier select: smallest chunk count whose GH fits in remaining workspace.
  int chunks = 16;
  for (int c = 1; c <= 8; c *= 2) {
    size_t gh_bytes = ((size_t)4096 / c) * 5120 * 2;
    if (base_bytes + gh_bytes <= ws_size) { chunks = c; break; }
  }
  if (chunks > 8) chunks = 8;  // best effort if ws_size is tiny
  const int rows = 4096 / chunks;

  dim3 tb(32, 8);
  cvt_f32_bf16<<<4096, 256, 0, stream>>>(hs, Xb);
  router_topk<<<4096, 64, 0, stream>>>(hs, rw, cw);

  for (int c = 0; c < chunks; c++) {
    const unsigned short* Xc = Xb + (size_t)c * rows * 1024;
    const float* cwc = cw + (size_t)c * rows * 8;
    float* outc = out + (size_t)c * rows * 1024;

    // phase 1: gate
    transpose_f32_bf16<<<dim3(16, 32, 8), tb, 0, stream>>>(wg, wT, 1024, 512);
    transpose_f32_bf16<<<dim3(32, 32, 1), tb, 0, stream>>>(wsg, wsT, 1024, 1024);
    gemm_gu<0><<<dim3(rows / 128, 40), 256, 0, stream>>>(Xc, wT, wsT, GH, cwc);

    // phase 2: up + fused silu/scale epilogue (H in place over G)
    transpose_f32_bf16<<<dim3(16, 32, 8), tb, 0, stream>>>(wu, wT, 1024, 512);
    transpose_f32_bf16<<<dim3(32, 32, 1), tb, 0, stream>>>(wsu, wsT, 1024, 1024);
    gemm_gu<1><<<dim3(rows / 128, 40), 256, 0, stream>>>(Xc, wT, wsT, GH, cwc);

    // phase 3: down
    transpose_f32_bf16<<<dim3(32, 16, 8), tb, 0, stream>>>(wd, wT, 512, 1024);
    transpose_f32_bf16<<<dim3(32, 32, 1), tb, 0, stream>>>(wsd, wsT, 1024, 1024);
    gemm_down<<<dim3(rows / 128, 8), 256, 0, stream>>>(GH, wT, wsT, outc);
  }
}

// Round 5
// 403.233 us; speedup vs baseline: 1.0150x; 1.0150x over previous
//
#include <hip/hip_runtime.h>

typedef __attribute__((ext_vector_type(8))) short bf16x8;
typedef __attribute__((ext_vector_type(4))) float floatx4;

static __device__ __forceinline__ float b2f(unsigned short u) {
  union { unsigned int i; float f; } v; v.i = ((unsigned int)u) << 16; return v.f;
}
static __device__ __forceinline__ unsigned short f2b(float f) {
  union { float f; unsigned int i; } v; v.f = f;
  unsigned int x = v.i;
  return (unsigned short)((x + 0x7fffu + ((x >> 16) & 1u)) >> 16);
}

#define GLDS(gp, lp) \
  __builtin_amdgcn_global_load_lds( \
      (const __attribute__((address_space(1))) unsigned int*)(gp), \
      (__attribute__((address_space(3))) unsigned int*)(lp), 16, 0, 0)

// ---------------- fp32 -> bf16 elementwise convert ------------------------------
__global__ void cvt_f32_bf16(const float* __restrict__ src,
                             unsigned short* __restrict__ dst) {
  int i = (blockIdx.x * 256 + threadIdx.x) * 4;
  float4 v = *(const float4*)(src + i);
  ushort4 o;
  o.x = f2b(v.x); o.y = f2b(v.y); o.z = f2b(v.z); o.w = f2b(v.w);
  *(ushort4*)(dst + i) = o;
}

// ------------- weight convert+transpose: fp32 [K,N] -> bf16 [N,K] ---------------
__global__ void transpose_f32_bf16(const float* __restrict__ src,
                                   unsigned short* __restrict__ dst, int K, int N) {
  __shared__ unsigned short tile[32][33];
  src += (size_t)blockIdx.z * K * N;
  dst += (size_t)blockIdx.z * K * N;
  const int bx = blockIdx.x * 32;  // N offset
  const int by = blockIdx.y * 32;  // K offset
  const int tx = threadIdx.x, ty = threadIdx.y;  // 32 x 8
#pragma unroll
  for (int i = 0; i < 4; i++)
    tile[ty + i * 8][tx] = f2b(src[(size_t)(by + ty + i * 8) * N + bx + tx]);
  __syncthreads();
#pragma unroll
  for (int i = 0; i < 4; i++)
    dst[(size_t)(bx + ty + i * 8) * K + by + tx] = tile[tx][ty + i * 8];
}

// ---------------- router: fp32 softmax over 8 logits, zero 2 smallest -----------
__global__ void router_topk(const float* __restrict__ X,
                            const float* __restrict__ RW,
                            float* __restrict__ cw) {
  const int t = blockIdx.x;
  const int lane = threadIdx.x;  // 64
  float acc[8];
#pragma unroll
  for (int e = 0; e < 8; e++) acc[e] = 0.f;
  for (int d = lane; d < 1024; d += 64) {
    float xv = X[(size_t)t * 1024 + d];
    const float* r = RW + d * 8;
    float4 r0 = *(const float4*)r;
    float4 r1 = *(const float4*)(r + 4);
    acc[0] += xv * r0.x; acc[1] += xv * r0.y;
    acc[2] += xv * r0.z; acc[3] += xv * r0.w;
    acc[4] += xv * r1.x; acc[5] += xv * r1.y;
    acc[6] += xv * r1.z; acc[7] += xv * r1.w;
  }
#pragma unroll
  for (int m = 1; m < 64; m <<= 1) {
#pragma unroll
    for (int e = 0; e < 8; e++) acc[e] += __shfl_xor(acc[e], m);
  }
  if (lane == 0) {
    float mx = acc[0];
#pragma unroll
    for (int e = 1; e < 8; e++) mx = fmaxf(mx, acc[e]);
    float prob[8], s = 0.f;
#pragma unroll
    for (int e = 0; e < 8; e++) { prob[e] = expf(acc[e] - mx); s += prob[e]; }
    float inv = 1.f / s;
#pragma unroll
    for (int e = 0; e < 8; e++) prob[e] *= inv;
    int m1 = 0;
#pragma unroll
    for (int e = 1; e < 8; e++) if (prob[e] < prob[m1]) m1 = e;
    int m2 = -1;
#pragma unroll
    for (int e = 0; e < 8; e++)
      if (e != m1 && (m2 < 0 || prob[e] < prob[m2])) m2 = e;
#pragma unroll
    for (int e = 0; e < 8; e++)
      cw[(size_t)t * 8 + e] = (e == m1 || e == m2) ? 0.f : prob[e];
  }
}

// ------------- fused gate+up GEMM: H = cw * silu(X@Wg) * (X@Wu) -----------------
// 128x128 tile, BK=32, 4 waves (2x2, 64x64 each). GLDS staging, XOR-swizzled.
// X bf16 [rows,1024]; B^T k-contiguous, ld 1024 (routed [E][512][1024] /
// shared [1024][1024]). Cols [0,4096) routed (expert n0>>9), [4096,5120) shared.
__global__ __launch_bounds__(256) void gemm_gu_fused(
    const unsigned short* __restrict__ X,
    const unsigned short* __restrict__ WgTe,
    const unsigned short* __restrict__ WgTs,
    const unsigned short* __restrict__ WuTe,
    const unsigned short* __restrict__ WuTs,
    unsigned short* __restrict__ H,
    const float* __restrict__ cw) {
  __shared__ __align__(16) unsigned short lA[128 * 32];
  __shared__ __align__(16) unsigned short lBg[128 * 32];
  __shared__ __align__(16) unsigned short lBu[128 * 32];
  const int tid = threadIdx.x;
  const int wid = tid >> 6, lane = tid & 63;
  const int lr = lane & 15, quad = lane >> 4;
  const int wm = wid >> 1, wn = wid & 1;
  const int m0 = blockIdx.x * 128;
  const int n0 = blockIdx.y * 128;

  const unsigned short *Bg, *Bu;
  int eidx = -1;
  if (n0 < 4096) {
    eidx = n0 >> 9;
    size_t off = ((size_t)eidx * 512 + (n0 & 511)) * 1024;
    Bg = WgTe + off; Bu = WuTe + off;
  } else {
    size_t off = (size_t)(n0 - 4096) * 1024;
    Bg = WgTs + off; Bu = WuTs + off;
  }

  floatx4 ag[4][4], au[4][4];
#pragma unroll
  for (int i = 0; i < 4; i++)
#pragma unroll
    for (int j = 0; j < 4; j++) { ag[i][j] = (floatx4)0.f; au[i][j] = (floatx4)0.f; }

  for (int k0 = 0; k0 < 1024; k0 += 32) {
    __syncthreads();
#pragma unroll
    for (int i = 0; i < 2; i++) {
      int c = i * 256 + tid;
      int row = c >> 2;
      int g = ((c & 3) ^ ((row >> 1) & 3)) << 3;  // swizzled global k-chunk
      unsigned short* lbase = (unsigned short*)0 + (size_t)(i * 256 + wid * 64) * 8;
      GLDS(X + (size_t)(m0 + row) * 1024 + k0 + g, lA + (size_t)(i * 256 + wid * 64) * 8);
      GLDS(Bg + (size_t)row * 1024 + k0 + g,       lBg + (size_t)(i * 256 + wid * 64) * 8);
      GLDS(Bu + (size_t)row * 1024 + k0 + g,       lBu + (size_t)(i * 256 + wid * 64) * 8);
      (void)lbase;
    }
    __syncthreads();
    bf16x8 af[4], bfr[4];
#pragma unroll
    for (int mt = 0; mt < 4; mt++) {
      int row = wm * 64 + mt * 16 + lr;
      af[mt] = *(const bf16x8*)(lA + row * 32 + ((quad ^ ((row >> 1) & 3)) << 3));
    }
#pragma unroll
    for (int nt = 0; nt < 4; nt++) {
      int row = wn * 64 + nt * 16 + lr;
      bfr[nt] = *(const bf16x8*)(lBg + row * 32 + ((quad ^ ((row >> 1) & 3)) << 3));
    }
#pragma unroll
    for (int mt = 0; mt < 4; mt++)
#pragma unroll
      for (int nt = 0; nt < 4; nt++)
        ag[mt][nt] = __builtin_amdgcn_mfma_f32_16x16x32_bf16(
            af[mt], bfr[nt], ag[mt][nt], 0, 0, 0);
#pragma unroll
    for (int nt = 0; nt < 4; nt++) {
      int row = wn * 64 + nt * 16 + lr;
      bfr[nt] = *(const bf16x8*)(lBu + row * 32 + ((quad ^ ((row >> 1) & 3)) << 3));
    }
#pragma unroll
    for (int mt = 0; mt < 4; mt++)
#pragma unroll
      for (int nt = 0; nt < 4; nt++)
        au[mt][nt] = __builtin_amdgcn_mfma_f32_16x16x32_bf16(
            af[mt], bfr[nt], au[mt][nt], 0, 0, 0);
  }

#pragma unroll
  for (int mt = 0; mt < 4; mt++) {
#pragma unroll
    for (int nt = 0; nt < 4; nt++) {
#pragma unroll
      for (int r = 0; r < 4; r++) {
        int row = m0 + wm * 64 + mt * 16 + quad * 4 + r;
        int col = n0 + wn * 64 + nt * 16 + lr;
        float g = ag[mt][nt][r];
        float u = au[mt][nt][r];
        float s = (eidx >= 0) ? cw[(size_t)row * 8 + eidx] : 1.0f;
        float silu = g / (1.0f + __expf(-g));
        H[(size_t)row * 5120 + col] = f2b(s * silu * u);
      }
    }
  }
}

// ---------------- down GEMM: Y[rows,1024] = H[rows,5120] @ Wd_cat (fp32 out) ----
// 64x64 tile, BK=64, 4 waves (2x2, 32x32 each). GLDS staging, XOR-swizzled.
// routed wdT [E][1024][512] (ld 512), shared wsdT [1024][1024] (ld 1024).
__global__ __launch_bounds__(256) void gemm_down64(
    const unsigned short* __restrict__ H,
    const unsigned short* __restrict__ WdTe,
    const unsigned short* __restrict__ WdTs,
    float* __restrict__ Y) {
  __shared__ __align__(16) unsigned short lA[64 * 64];
  __shared__ __align__(16) unsigned short lB[64 * 64];
  const int tid = threadIdx.x;
  const int wid = tid >> 6, lane = tid & 63;
  const int lr = lane & 15, quad = lane >> 4;
  const int wm = wid >> 1, wn = wid & 1;
  const int m0 = blockIdx.x * 64;
  const int n0 = blockIdx.y * 64;

  floatx4 acc[2][2];
#pragma unroll
  for (int i = 0; i < 2; i++)
#pragma unroll
    for (int j = 0; j < 2; j++) acc[i][j] = (floatx4)0.f;

  for (int k0 = 0; k0 < 5120; k0 += 64) {
    __syncthreads();
#pragma unroll
    for (int i = 0; i < 2; i++) {
      int c = i * 256 + tid;
      int row = c >> 3;                       // 0..63
      int g = ((c & 7) ^ (row & 7)) << 3;     // swizzled global k-chunk
      GLDS(H + (size_t)(m0 + row) * 5120 + k0 + g,
           lA + (size_t)(i * 256 + wid * 64) * 8);
      const unsigned short* gpb;
      if (k0 < 4096) {
        gpb = WdTe + (size_t)(k0 >> 9) * (1024 * 512) +
              (size_t)(n0 + row) * 512 + (k0 & 511) + g;
      } else {
        gpb = WdTs + (size_t)(n0 + row) * 1024 + (k0 - 4096) + g;
      }
      GLDS(gpb, lB + (size_t)(i * 256 + wid * 64) * 8);
    }
    __syncthreads();
    bf16x8 af[2][2], bfr[2][2];
#pragma unroll
    for (int mt = 0; mt < 2; mt++) {
      int row = wm * 32 + mt * 16 + lr;
#pragma unroll
      for (int kt = 0; kt < 2; kt++)
        af[mt][kt] = *(const bf16x8*)(lA + row * 64 +
                                      ((((kt << 2) + quad) ^ (row & 7)) << 3));
    }
#pragma unroll
    for (int nt = 0; nt < 2; nt++) {
      int row = wn * 32 + nt * 16 + lr;
#pragma unroll
      for (int kt = 0; kt < 2; kt++)
        bfr[nt][kt] = *(const bf16x8*)(lB + row * 64 +
                                       ((((kt << 2) + quad) ^ (row & 7)) << 3));
    }
#pragma unroll
    for (int kt = 0; kt < 2; kt++)
#pragma unroll
      for (int mt = 0; mt < 2; mt++)
#pragma unroll
        for (int nt = 0; nt < 2; nt++)
          acc[mt][nt] = __builtin_amdgcn_mfma_f32_16x16x32_bf16(
              af[mt][kt], bfr[nt][kt], acc[mt][nt], 0, 0, 0);
  }

#pragma unroll
  for (int mt = 0; mt < 2; mt++)
#pragma unroll
    for (int nt = 0; nt < 2; nt++)
#pragma unroll
      for (int r = 0; r < 4; r++) {
        int row = m0 + wm * 32 + mt * 16 + quad * 4 + r;
        int col = n0 + wn * 32 + nt * 16 + lr;
        Y[(size_t)row * 1024 + col] = acc[mt][nt][r];
      }
}

extern "C" void kernel_launch(void* const* d_in, const int* in_sizes, int n_in,
                              void* d_out, int out_size, void* d_ws, size_t ws_size,
                              hipStream_t stream) {
  const float* hs  = (const float*)d_in[0];
  const float* rw  = (const float*)d_in[1];
  const float* wg  = (const float*)d_in[2];
  const float* wu  = (const float*)d_in[3];
  const float* wd  = (const float*)d_in[4];
  const float* wsg = (const float*)d_in[5];
  const float* wsu = (const float*)d_in[6];
  const float* wsd = (const float*)d_in[7];
  float* out = (float*)d_out;

  // workspace: cw 128K | Xb 8M | wgT 8M | wuT 8M | wsgT 2M | wsuT 2M |
  //            wdT 8M | wsdT 2M | GH 40/c M.  base = 38.125 MB.
  char* p = (char*)d_ws;
  float* cw = (float*)p;                    p += (size_t)4096 * 8 * 4;
  unsigned short* Xb   = (unsigned short*)p; p += (size_t)4096 * 1024 * 2;
  unsigned short* wgT  = (unsigned short*)p; p += (size_t)8 * 512 * 1024 * 2;
  unsigned short* wuT  = (unsigned short*)p; p += (size_t)8 * 512 * 1024 * 2;
  unsigned short* wsgT = (unsigned short*)p; p += (size_t)1024 * 1024 * 2;
  unsigned short* wsuT = (unsigned short*)p; p += (size_t)1024 * 1024 * 2;
  unsigned short* wdT  = (unsigned short*)p; p += (size_t)8 * 1024 * 512 * 2;
  unsigned short* wsdT = (unsigned short*)p; p += (size_t)1024 * 1024 * 2;
  unsigned short* GH   = (unsigned short*)p;
  const size_t base_bytes = (size_t)(p - (char*)d_ws);

  int chunks = 8;
  for (int c = 1; c <= 8; c *= 2) {
    size_t gh_bytes = ((size_t)4096 / c) * 5120 * 2;
    if (base_bytes + gh_bytes <= ws_size) { chunks = c; break; }
  }
  const int rows = 4096 / chunks;

  dim3 tb(32, 8);
  cvt_f32_bf16<<<4096, 256, 0, stream>>>(hs, Xb);
  router_topk<<<4096, 64, 0, stream>>>(hs, rw, cw);
  transpose_f32_bf16<<<dim3(16, 32, 8), tb, 0, stream>>>(wg, wgT, 1024, 512);
  transpose_f32_bf16<<<dim3(16, 32, 8), tb, 0, stream>>>(wu, wuT, 1024, 512);
  transpose_f32_bf16<<<dim3(32, 16, 8), tb, 0, stream>>>(wd, wdT, 512, 1024);
  transpose_f32_bf16<<<dim3(32, 32, 1), tb, 0, stream>>>(wsg, wsgT, 1024, 1024);
  transpose_f32_bf16<<<dim3(32, 32, 1), tb, 0, stream>>>(wsu, wsuT, 1024, 1024);
  transpose_f32_bf16<<<dim3(32, 32, 1), tb, 0, stream>>>(wsd, wsdT, 1024, 1024);

  for (int c = 0; c < chunks; c++) {
    const unsigned short* Xc = Xb + (size_t)c * rows * 1024;
    const float* cwc = cw + (size_t)c * rows * 8;
    float* outc = out + (size_t)c * rows * 1024;
    gemm_gu_fused<<<dim3(rows / 128, 40), 256, 0, stream>>>(
        Xc, wgT, wsgT, wuT, wsuT, GH, cwc);
    gemm_down64<<<dim3(rows / 64, 16), 256, 0, stream>>>(GH, wdT, wsdT, outc);
  }
}

// Round 6
// 317.304 us; speedup vs baseline: 1.2899x; 1.2708x over previous
//
#include <hip/hip_runtime.h>

typedef __attribute__((ext_vector_type(8))) short bf16x8;
typedef __attribute__((ext_vector_type(4))) float floatx4;

static __device__ __forceinline__ float b2f(unsigned short u) {
  union { unsigned int i; float f; } v; v.i = ((unsigned int)u) << 16; return v.f;
}
static __device__ __forceinline__ unsigned short f2b(float f) {
  union { float f; unsigned int i; } v; v.f = f;
  unsigned int x = v.i;
  return (unsigned short)((x + 0x7fffu + ((x >> 16) & 1u)) >> 16);
}

#define GLDS(gp, lp) \
  __builtin_amdgcn_global_load_lds( \
      (const __attribute__((address_space(1))) unsigned int*)(gp), \
      (__attribute__((address_space(3))) unsigned int*)(lp), 16, 0, 0)

// ---------------- fp32 -> bf16 elementwise convert ------------------------------
__global__ void cvt_f32_bf16(const float* __restrict__ src,
                             unsigned short* __restrict__ dst) {
  int i = (blockIdx.x * 256 + threadIdx.x) * 4;
  float4 v = *(const float4*)(src + i);
  ushort4 o;
  o.x = f2b(v.x); o.y = f2b(v.y); o.z = f2b(v.z); o.w = f2b(v.w);
  *(ushort4*)(dst + i) = o;
}

// ------------- weight convert+transpose: fp32 [K,N] -> bf16 [N,K] ---------------
__global__ void transpose_f32_bf16(const float* __restrict__ src,
                                   unsigned short* __restrict__ dst, int K, int N) {
  __shared__ unsigned short tile[32][33];
  src += (size_t)blockIdx.z * K * N;
  dst += (size_t)blockIdx.z * K * N;
  const int bx = blockIdx.x * 32;  // N offset
  const int by = blockIdx.y * 32;  // K offset
  const int tx = threadIdx.x, ty = threadIdx.y;  // 32 x 8
#pragma unroll
  for (int i = 0; i < 4; i++)
    tile[ty + i * 8][tx] = f2b(src[(size_t)(by + ty + i * 8) * N + bx + tx]);
  __syncthreads();
#pragma unroll
  for (int i = 0; i < 4; i++)
    dst[(size_t)(bx + ty + i * 8) * K + by + tx] = tile[tx][ty + i * 8];
}

// ---------------- router: fp32 softmax over 8 logits, zero 2 smallest -----------
__global__ void router_topk(const float* __restrict__ X,
                            const float* __restrict__ RW,
                            float* __restrict__ cw) {
  const int t = blockIdx.x;
  const int lane = threadIdx.x;  // 64
  float acc[8];
#pragma unroll
  for (int e = 0; e < 8; e++) acc[e] = 0.f;
  for (int d = lane; d < 1024; d += 64) {
    float xv = X[(size_t)t * 1024 + d];
    const float* r = RW + d * 8;
    float4 r0 = *(const float4*)r;
    float4 r1 = *(const float4*)(r + 4);
    acc[0] += xv * r0.x; acc[1] += xv * r0.y;
    acc[2] += xv * r0.z; acc[3] += xv * r0.w;
    acc[4] += xv * r1.x; acc[5] += xv * r1.y;
    acc[6] += xv * r1.z; acc[7] += xv * r1.w;
  }
#pragma unroll
  for (int m = 1; m < 64; m <<= 1) {
#pragma unroll
    for (int e = 0; e < 8; e++) acc[e] += __shfl_xor(acc[e], m);
  }
  if (lane == 0) {
    float mx = acc[0];
#pragma unroll
    for (int e = 1; e < 8; e++) mx = fmaxf(mx, acc[e]);
    float prob[8], s = 0.f;
#pragma unroll
    for (int e = 0; e < 8; e++) { prob[e] = expf(acc[e] - mx); s += prob[e]; }
    float inv = 1.f / s;
#pragma unroll
    for (int e = 0; e < 8; e++) prob[e] *= inv;
    int m1 = 0;
#pragma unroll
    for (int e = 1; e < 8; e++) if (prob[e] < prob[m1]) m1 = e;
    int m2 = -1;
#pragma unroll
    for (int e = 0; e < 8; e++)
      if (e != m1 && (m2 < 0 || prob[e] < prob[m2])) m2 = e;
#pragma unroll
    for (int e = 0; e < 8; e++)
      cw[(size_t)t * 8 + e] = (e == m1 || e == m2) ? 0.f : prob[e];
  }
}

// ------------- fused gate+up GEMM: H = cw * silu(X@Wg) * (X@Wu) -----------------
// Block tile 128(M)x64(N), BK=32, 4 waves (2x2, wave tile 64x32).
// Acc: 8 frags g + 8 frags u = 64 regs/lane (occupancy: ~2 blocks/CU).
// X bf16 [rows,1024]; B^T k-contiguous, ld 1024 (routed [E][512][1024] /
// shared [1024][1024]). Cols [0,4096) routed (expert n0>>9), [4096,5120) shared.
__global__ __launch_bounds__(256) void gemm_gu_fused(
    const unsigned short* __restrict__ X,
    const unsigned short* __restrict__ WgTe,
    const unsigned short* __restrict__ WgTs,
    const unsigned short* __restrict__ WuTe,
    const unsigned short* __restrict__ WuTs,
    unsigned short* __restrict__ H,
    const float* __restrict__ cw) {
  __shared__ __align__(16) unsigned short lA[128 * 32];
  __shared__ __align__(16) unsigned short lBg[64 * 32];
  __shared__ __align__(16) unsigned short lBu[64 * 32];
  const int tid = threadIdx.x;
  const int wid = tid >> 6, lane = tid & 63;
  const int lr = lane & 15, quad = lane >> 4;
  const int wm = wid >> 1, wn = wid & 1;
  const int m0 = blockIdx.x * 128;
  const int n0 = blockIdx.y * 64;

  const unsigned short *Bg, *Bu;
  int eidx = -1;
  if (n0 < 4096) {
    eidx = n0 >> 9;
    size_t off = ((size_t)eidx * 512 + (n0 & 511)) * 1024;
    Bg = WgTe + off; Bu = WuTe + off;
  } else {
    size_t off = (size_t)(n0 - 4096) * 1024;
    Bg = WgTs + off; Bu = WuTs + off;
  }

  floatx4 ag[4][2], au[4][2];
#pragma unroll
  for (int i = 0; i < 4; i++)
#pragma unroll
    for (int j = 0; j < 2; j++) { ag[i][j] = (floatx4)0.f; au[i][j] = (floatx4)0.f; }

  for (int k0 = 0; k0 < 1024; k0 += 32) {
    __syncthreads();
    {
      // A: 128x32 = 512 16B-chunks; Bg/Bu: 64x32 = 256 chunks each.
#pragma unroll
      for (int i = 0; i < 2; i++) {
        int c = i * 256 + tid;
        int row = c >> 2;
        int g = ((c & 3) ^ ((row >> 1) & 3)) << 3;
        GLDS(X + (size_t)(m0 + row) * 1024 + k0 + g,
             lA + (size_t)(i * 256 + wid * 64) * 8);
      }
      int c = tid;
      int row = c >> 2;
      int g = ((c & 3) ^ ((row >> 1) & 3)) << 3;
      GLDS(Bg + (size_t)row * 1024 + k0 + g, lBg + (size_t)(wid * 64) * 8);
      GLDS(Bu + (size_t)row * 1024 + k0 + g, lBu + (size_t)(wid * 64) * 8);
    }
    __syncthreads();
    bf16x8 af[4], bg[2], bu[2];
#pragma unroll
    for (int mt = 0; mt < 4; mt++) {
      int row = wm * 64 + mt * 16 + lr;
      af[mt] = *(const bf16x8*)(lA + row * 32 + ((quad ^ ((row >> 1) & 3)) << 3));
    }
#pragma unroll
    for (int nt = 0; nt < 2; nt++) {
      int row = wn * 32 + nt * 16 + lr;
      int o = row * 32 + ((quad ^ ((row >> 1) & 3)) << 3);
      bg[nt] = *(const bf16x8*)(lBg + o);
      bu[nt] = *(const bf16x8*)(lBu + o);
    }
#pragma unroll
    for (int mt = 0; mt < 4; mt++)
#pragma unroll
      for (int nt = 0; nt < 2; nt++) {
        ag[mt][nt] = __builtin_amdgcn_mfma_f32_16x16x32_bf16(
            af[mt], bg[nt], ag[mt][nt], 0, 0, 0);
        au[mt][nt] = __builtin_amdgcn_mfma_f32_16x16x32_bf16(
            af[mt], bu[nt], au[mt][nt], 0, 0, 0);
      }
  }

#pragma unroll
  for (int mt = 0; mt < 4; mt++) {
#pragma unroll
    for (int nt = 0; nt < 2; nt++) {
#pragma unroll
      for (int r = 0; r < 4; r++) {
        int row = m0 + wm * 64 + mt * 16 + quad * 4 + r;
        int col = n0 + wn * 32 + nt * 16 + lr;
        float g = ag[mt][nt][r];
        float u = au[mt][nt][r];
        float s = (eidx >= 0) ? cw[(size_t)row * 8 + eidx] : 1.0f;
        float silu = g / (1.0f + __expf(-g));
        H[(size_t)row * 5120 + col] = f2b(s * silu * u);
      }
    }
  }
}

// ---------------- down GEMM: Y[rows,1024] = H[rows,5120] @ Wd_cat (fp32 out) ----
// Block tile 128(M)x64(N), BK=64, 4 waves (2x2, wave tile 64x32).
// routed wdT [E][1024][512] (ld 512), shared wsdT [1024][1024] (ld 1024).
__global__ __launch_bounds__(256) void gemm_down(
    const unsigned short* __restrict__ H,
    const unsigned short* __restrict__ WdTe,
    const unsigned short* __restrict__ WdTs,
    float* __restrict__ Y) {
  __shared__ __align__(16) unsigned short lA[128 * 64];
  __shared__ __align__(16) unsigned short lB[64 * 64];
  const int tid = threadIdx.x;
  const int wid = tid >> 6, lane = tid & 63;
  const int lr = lane & 15, quad = lane >> 4;
  const int wm = wid >> 1, wn = wid & 1;
  const int m0 = blockIdx.x * 128;
  const int n0 = blockIdx.y * 64;

  floatx4 acc[4][2];
#pragma unroll
  for (int i = 0; i < 4; i++)
#pragma unroll
    for (int j = 0; j < 2; j++) acc[i][j] = (floatx4)0.f;

  for (int k0 = 0; k0 < 5120; k0 += 64) {
    __syncthreads();
    // A: 128x64 = 1024 chunks (4/thread); B: 64x64 = 512 chunks (2/thread).
#pragma unroll
    for (int i = 0; i < 4; i++) {
      int c = i * 256 + tid;
      int row = c >> 3;
      int g = ((c & 7) ^ (row & 7)) << 3;
      GLDS(H + (size_t)(m0 + row) * 5120 + k0 + g,
           lA + (size_t)(i * 256 + wid * 64) * 8);
    }
#pragma unroll
    for (int i = 0; i < 2; i++) {
      int c = i * 256 + tid;
      int row = c >> 3;
      int g = ((c & 7) ^ (row & 7)) << 3;
      const unsigned short* gpb;
      if (k0 < 4096) {
        gpb = WdTe + (size_t)(k0 >> 9) * (1024 * 512) +
              (size_t)(n0 + row) * 512 + (k0 & 511) + g;
      } else {
        gpb = WdTs + (size_t)(n0 + row) * 1024 + (k0 - 4096) + g;
      }
      GLDS(gpb, lB + (size_t)(i * 256 + wid * 64) * 8);
    }
    __syncthreads();
    bf16x8 af[4][2], bfr[2][2];
#pragma unroll
    for (int mt = 0; mt < 4; mt++) {
      int row = wm * 64 + mt * 16 + lr;
#pragma unroll
      for (int kt = 0; kt < 2; kt++)
        af[mt][kt] = *(const bf16x8*)(lA + row * 64 +
                                      ((((kt << 2) + quad) ^ (row & 7)) << 3));
    }
#pragma unroll
    for (int nt = 0; nt < 2; nt++) {
      int row = wn * 32 + nt * 16 + lr;
#pragma unroll
      for (int kt = 0; kt < 2; kt++)
        bfr[nt][kt] = *(const bf16x8*)(lB + row * 64 +
                                       ((((kt << 2) + quad) ^ (row & 7)) << 3));
    }
#pragma unroll
    for (int kt = 0; kt < 2; kt++)
#pragma unroll
      for (int mt = 0; mt < 4; mt++)
#pragma unroll
        for (int nt = 0; nt < 2; nt++)
          acc[mt][nt] = __builtin_amdgcn_mfma_f32_16x16x32_bf16(
              af[mt][kt], bfr[nt][kt], acc[mt][nt], 0, 0, 0);
  }

#pragma unroll
  for (int mt = 0; mt < 4; mt++)
#pragma unroll
    for (int nt = 0; nt < 2; nt++)
#pragma unroll
      for (int r = 0; r < 4; r++) {
        int row = m0 + wm * 64 + mt * 16 + quad * 4 + r;
        int col = n0 + wn * 32 + nt * 16 + lr;
        Y[(size_t)row * 1024 + col] = acc[mt][nt][r];
      }
}

extern "C" void kernel_launch(void* const* d_in, const int* in_sizes, int n_in,
                              void* d_out, int out_size, void* d_ws, size_t ws_size,
                              hipStream_t stream) {
  const float* hs  = (const float*)d_in[0];
  const float* rw  = (const float*)d_in[1];
  const float* wg  = (const float*)d_in[2];
  const float* wu  = (const float*)d_in[3];
  const float* wd  = (const float*)d_in[4];
  const float* wsg = (const float*)d_in[5];
  const float* wsu = (const float*)d_in[6];
  const float* wsd = (const float*)d_in[7];
  float* out = (float*)d_out;

  // workspace: cw 128K | Xb 8M | wgT 8M | wuT 8M | wsgT 2M | wsuT 2M |
  //            wdT 8M | wsdT 2M | GH 40/c M.  base = 38.125 MB.
  char* p = (char*)d_ws;
  float* cw = (float*)p;                    p += (size_t)4096 * 8 * 4;
  unsigned short* Xb   = (unsigned short*)p; p += (size_t)4096 * 1024 * 2;
  unsigned short* wgT  = (unsigned short*)p; p += (size_t)8 * 512 * 1024 * 2;
  unsigned short* wuT  = (unsigned short*)p; p += (size_t)8 * 512 * 1024 * 2;
  unsigned short* wsgT = (unsigned short*)p; p += (size_t)1024 * 1024 * 2;
  unsigned short* wsuT = (unsigned short*)p; p += (size_t)1024 * 1024 * 2;
  unsigned short* wdT  = (unsigned short*)p; p += (size_t)8 * 1024 * 512 * 2;
  unsigned short* wsdT = (unsigned short*)p; p += (size_t)1024 * 1024 * 2;
  unsigned short* GH   = (unsigned short*)p;
  const size_t base_bytes = (size_t)(p - (char*)d_ws);

  int chunks = 8;
  for (int c = 1; c <= 8; c *= 2) {
    size_t gh_bytes = ((size_t)4096 / c) * 5120 * 2;
    if (base_bytes + gh_bytes <= ws_size) { chunks = c; break; }
  }
  const int rows = 4096 / chunks;

  dim3 tb(32, 8);
  cvt_f32_bf16<<<4096, 256, 0, stream>>>(hs, Xb);
  router_topk<<<4096, 64, 0, stream>>>(hs, rw, cw);
  transpose_f32_bf16<<<dim3(16, 32, 8), tb, 0, stream>>>(wg, wgT, 1024, 512);
  transpose_f32_bf16<<<dim3(16, 32, 8), tb, 0, stream>>>(wu, wuT, 1024, 512);
  transpose_f32_bf16<<<dim3(32, 16, 8), tb, 0, stream>>>(wd, wdT, 512, 1024);
  transpose_f32_bf16<<<dim3(32, 32, 1), tb, 0, stream>>>(wsg, wsgT, 1024, 1024);
  transpose_f32_bf16<<<dim3(32, 32, 1), tb, 0, stream>>>(wsu, wsuT, 1024, 1024);
  transpose_f32_bf16<<<dim3(32, 32, 1), tb, 0, stream>>>(wsd, wsdT, 1024, 1024);

  for (int c = 0; c < chunks; c++) {
    const unsigned short* Xc = Xb + (size_t)c * rows * 1024;
    const float* cwc = cw + (size_t)c * rows * 8;
    float* outc = out + (size_t)c * rows * 1024;
    gemm_gu_fused<<<dim3(rows / 128, 80), 256, 0, stream>>>(
        Xc, wgT, wsgT, wuT, wsuT, GH, cwc);
    gemm_down<<<dim3(rows / 128, 16), 256, 0, stream>>>(GH, wdT, wsdT, outc);
  }
}

// Round 7
// 312.996 us; speedup vs baseline: 1.3076x; 1.0138x over previous
//
#include <hip/hip_runtime.h>

typedef __attribute__((ext_vector_type(8))) short bf16x8;
typedef __attribute__((ext_vector_type(4))) float floatx4;

static __device__ __forceinline__ float b2f(unsigned short u) {
  union { unsigned int i; float f; } v; v.i = ((unsigned int)u) << 16; return v.f;
}
static __device__ __forceinline__ unsigned short f2b(float f) {
  union { float f; unsigned int i; } v; v.f = f;
  unsigned int x = v.i;
  return (unsigned short)((x + 0x7fffu + ((x >> 16) & 1u)) >> 16);
}

#define GLDS(gp, lp) \
  __builtin_amdgcn_global_load_lds( \
      (const __attribute__((address_space(1))) unsigned int*)(gp), \
      (__attribute__((address_space(3))) unsigned int*)(lp), 16, 0, 0)

// XCD-aware swizzle: dispatch round-robins linear block id across 8 XCDs
// (lin%8 == XCD, learn_hip m09). Map so each XCD owns m-strips with
// m%8==xcd, strip index varying fastest -> A-strips resident in that XCD's
// 4MB L2 while B streams. Perf heuristic only; any mapping is correct.
static __device__ __forceinline__ void swizzle_mn(int lin, int Mb, int Nb,
                                                  int& m_idx, int& n_idx) {
  if ((Mb & 7) == 0) {
    int xcd = lin & 7;
    int idx = lin >> 3;          // [0, Mb*Nb/8)
    int nstrips = Mb >> 3;       // m-strips owned by this XCD
    m_idx = (idx % nstrips) * 8 + xcd;
    n_idx = idx / nstrips;       // [0, Nb)
  } else {
    m_idx = lin % Mb;
    n_idx = lin / Mb;
  }
}

// ---------------- fp32 -> bf16 elementwise convert ------------------------------
__global__ void cvt_f32_bf16(const float* __restrict__ src,
                             unsigned short* __restrict__ dst) {
  int i = (blockIdx.x * 256 + threadIdx.x) * 4;
  float4 v = *(const float4*)(src + i);
  ushort4 o;
  o.x = f2b(v.x); o.y = f2b(v.y); o.z = f2b(v.z); o.w = f2b(v.w);
  *(ushort4*)(dst + i) = o;
}

// ------------- weight convert+transpose: fp32 [K,N] -> bf16 [N,K] ---------------
// Generic batched form: z selects among up to 2 src/dst pairs, nz0 = #mats in
// pair 0. Used to fuse gate+up routed transposes (and the 3 shared ones).
__global__ void transpose_f32_bf16_2(const float* __restrict__ sA,
                                     unsigned short* __restrict__ dA, int nzA,
                                     const float* __restrict__ sB,
                                     unsigned short* __restrict__ dB,
                                     int K, int N) {
  __shared__ unsigned short tile[32][33];
  int z = blockIdx.z;
  const float* src;
  unsigned short* dst;
  if (z < nzA) { src = sA + (size_t)z * K * N; dst = dA + (size_t)z * K * N; }
  else { src = sB + (size_t)(z - nzA) * K * N; dst = dB + (size_t)(z - nzA) * K * N; }
  const int bx = blockIdx.x * 32;  // N offset
  const int by = blockIdx.y * 32;  // K offset
  const int tx = threadIdx.x, ty = threadIdx.y;  // 32 x 8
#pragma unroll
  for (int i = 0; i < 4; i++)
    tile[ty + i * 8][tx] = f2b(src[(size_t)(by + ty + i * 8) * N + bx + tx]);
  __syncthreads();
#pragma unroll
  for (int i = 0; i < 4; i++)
    dst[(size_t)(bx + ty + i * 8) * K + by + tx] = tile[tx][ty + i * 8];
}

// 3 independent 1024x1024 transposes in one launch (z = 0,1,2)
__global__ void transpose3_1024(const float* __restrict__ s0,
                                const float* __restrict__ s1,
                                const float* __restrict__ s2,
                                unsigned short* __restrict__ d0,
                                unsigned short* __restrict__ d1,
                                unsigned short* __restrict__ d2) {
  __shared__ unsigned short tile[32][33];
  const float* src = (blockIdx.z == 0) ? s0 : (blockIdx.z == 1) ? s1 : s2;
  unsigned short* dst = (blockIdx.z == 0) ? d0 : (blockIdx.z == 1) ? d1 : d2;
  const int bx = blockIdx.x * 32;
  const int by = blockIdx.y * 32;
  const int tx = threadIdx.x, ty = threadIdx.y;
#pragma unroll
  for (int i = 0; i < 4; i++)
    tile[ty + i * 8][tx] = f2b(src[(size_t)(by + ty + i * 8) * 1024 + bx + tx]);
  __syncthreads();
#pragma unroll
  for (int i = 0; i < 4; i++)
    dst[(size_t)(bx + ty + i * 8) * 1024 + by + tx] = tile[tx][ty + i * 8];
}

// ---------------- router: fp32 softmax over 8 logits, zero 2 smallest -----------
__global__ void router_topk(const float* __restrict__ X,
                            const float* __restrict__ RW,
                            float* __restrict__ cw) {
  const int t = blockIdx.x;
  const int lane = threadIdx.x;  // 64
  float acc[8];
#pragma unroll
  for (int e = 0; e < 8; e++) acc[e] = 0.f;
  for (int d = lane; d < 1024; d += 64) {
    float xv = X[(size_t)t * 1024 + d];
    const float* r = RW + d * 8;
    float4 r0 = *(const float4*)r;
    float4 r1 = *(const float4*)(r + 4);
    acc[0] += xv * r0.x; acc[1] += xv * r0.y;
    acc[2] += xv * r0.z; acc[3] += xv * r0.w;
    acc[4] += xv * r1.x; acc[5] += xv * r1.y;
    acc[6] += xv * r1.z; acc[7] += xv * r1.w;
  }
#pragma unroll
  for (int m = 1; m < 64; m <<= 1) {
#pragma unroll
    for (int e = 0; e < 8; e++) acc[e] += __shfl_xor(acc[e], m);
  }
  if (lane == 0) {
    float mx = acc[0];
#pragma unroll
    for (int e = 1; e < 8; e++) mx = fmaxf(mx, acc[e]);
    float prob[8], s = 0.f;
#pragma unroll
    for (int e = 0; e < 8; e++) { prob[e] = expf(acc[e] - mx); s += prob[e]; }
    float inv = 1.f / s;
#pragma unroll
    for (int e = 0; e < 8; e++) prob[e] *= inv;
    int m1 = 0;
#pragma unroll
    for (int e = 1; e < 8; e++) if (prob[e] < prob[m1]) m1 = e;
    int m2 = -1;
#pragma unroll
    for (int e = 0; e < 8; e++)
      if (e != m1 && (m2 < 0 || prob[e] < prob[m2])) m2 = e;
#pragma unroll
    for (int e = 0; e < 8; e++)
      cw[(size_t)t * 8 + e] = (e == m1 || e == m2) ? 0.f : prob[e];
  }
}

// ------------- fused gate+up GEMM: H = cw * silu(X@Wg) * (X@Wu) -----------------
// Block tile 128(M)x64(N), BK=32, 4 waves (2x2, wave tile 64x32). Flat grid,
// XCD swizzle. Cols [0,4096) routed (expert n0>>9), [4096,5120) shared.
__global__ __launch_bounds__(256) void gemm_gu_fused(
    const unsigned short* __restrict__ X,
    const unsigned short* __restrict__ WgTe,
    const unsigned short* __restrict__ WgTs,
    const unsigned short* __restrict__ WuTe,
    const unsigned short* __restrict__ WuTs,
    unsigned short* __restrict__ H,
    const float* __restrict__ cw, int Mb) {
  __shared__ __align__(16) unsigned short lA[128 * 32];
  __shared__ __align__(16) unsigned short lBg[64 * 32];
  __shared__ __align__(16) unsigned short lBu[64 * 32];
  const int tid = threadIdx.x;
  const int wid = tid >> 6, lane = tid & 63;
  const int lr = lane & 15, quad = lane >> 4;
  const int wm = wid >> 1, wn = wid & 1;
  int m_idx, n_idx;
  swizzle_mn(blockIdx.x, Mb, 80, m_idx, n_idx);
  const int m0 = m_idx * 128;
  const int n0 = n_idx * 64;

  const unsigned short *Bg, *Bu;
  int eidx = -1;
  if (n0 < 4096) {
    eidx = n0 >> 9;
    size_t off = ((size_t)eidx * 512 + (n0 & 511)) * 1024;
    Bg = WgTe + off; Bu = WuTe + off;
  } else {
    size_t off = (size_t)(n0 - 4096) * 1024;
    Bg = WgTs + off; Bu = WuTs + off;
  }

  floatx4 ag[4][2], au[4][2];
#pragma unroll
  for (int i = 0; i < 4; i++)
#pragma unroll
    for (int j = 0; j < 2; j++) { ag[i][j] = (floatx4)0.f; au[i][j] = (floatx4)0.f; }

  for (int k0 = 0; k0 < 1024; k0 += 32) {
    __syncthreads();
    {
#pragma unroll
      for (int i = 0; i < 2; i++) {
        int c = i * 256 + tid;
        int row = c >> 2;
        int g = ((c & 3) ^ ((row >> 1) & 3)) << 3;
        GLDS(X + (size_t)(m0 + row) * 1024 + k0 + g,
             lA + (size_t)(i * 256 + wid * 64) * 8);
      }
      int c = tid;
      int row = c >> 2;
      int g = ((c & 3) ^ ((row >> 1) & 3)) << 3;
      GLDS(Bg + (size_t)row * 1024 + k0 + g, lBg + (size_t)(wid * 64) * 8);
      GLDS(Bu + (size_t)row * 1024 + k0 + g, lBu + (size_t)(wid * 64) * 8);
    }
    __syncthreads();
    bf16x8 af[4], bg[2], bu[2];
#pragma unroll
    for (int mt = 0; mt < 4; mt++) {
      int row = wm * 64 + mt * 16 + lr;
      af[mt] = *(const bf16x8*)(lA + row * 32 + ((quad ^ ((row >> 1) & 3)) << 3));
    }
#pragma unroll
    for (int nt = 0; nt < 2; nt++) {
      int row = wn * 32 + nt * 16 + lr;
      int o = row * 32 + ((quad ^ ((row >> 1) & 3)) << 3);
      bg[nt] = *(const bf16x8*)(lBg + o);
      bu[nt] = *(const bf16x8*)(lBu + o);
    }
#pragma unroll
    for (int mt = 0; mt < 4; mt++)
#pragma unroll
      for (int nt = 0; nt < 2; nt++) {
        ag[mt][nt] = __builtin_amdgcn_mfma_f32_16x16x32_bf16(
            af[mt], bg[nt], ag[mt][nt], 0, 0, 0);
        au[mt][nt] = __builtin_amdgcn_mfma_f32_16x16x32_bf16(
            af[mt], bu[nt], au[mt][nt], 0, 0, 0);
      }
  }

#pragma unroll
  for (int mt = 0; mt < 4; mt++) {
#pragma unroll
    for (int nt = 0; nt < 2; nt++) {
#pragma unroll
      for (int r = 0; r < 4; r++) {
        int row = m0 + wm * 64 + mt * 16 + quad * 4 + r;
        int col = n0 + wn * 32 + nt * 16 + lr;
        float g = ag[mt][nt][r];
        float u = au[mt][nt][r];
        float s = (eidx >= 0) ? cw[(size_t)row * 8 + eidx] : 1.0f;
        float silu = g / (1.0f + __expf(-g));
        H[(size_t)row * 5120 + col] = f2b(s * silu * u);
      }
    }
  }
}

// ---------------- down GEMM: Y[rows,1024] = H[rows,5120] @ Wd_cat (fp32 out) ----
// Block tile 128(M)x64(N), BK=64, 4 waves (2x2, wave tile 64x32). Flat grid,
// XCD swizzle. routed wdT [E][1024][512] (ld 512), shared wsdT [1024][1024].
__global__ __launch_bounds__(256) void gemm_down(
    const unsigned short* __restrict__ H,
    const unsigned short* __restrict__ WdTe,
    const unsigned short* __restrict__ WdTs,
    float* __restrict__ Y, int Mb) {
  __shared__ __align__(16) unsigned short lA[128 * 64];
  __shared__ __align__(16) unsigned short lB[64 * 64];
  const int tid = threadIdx.x;
  const int wid = tid >> 6, lane = tid & 63;
  const int lr = lane & 15, quad = lane >> 4;
  const int wm = wid >> 1, wn = wid & 1;
  int m_idx, n_idx;
  swizzle_mn(blockIdx.x, Mb, 16, m_idx, n_idx);
  const int m0 = m_idx * 128;
  const int n0 = n_idx * 64;

  floatx4 acc[4][2];
#pragma unroll
  for (int i = 0; i < 4; i++)
#pragma unroll
    for (int j = 0; j < 2; j++) acc[i][j] = (floatx4)0.f;

  for (int k0 = 0; k0 < 5120; k0 += 64) {
    __syncthreads();
#pragma unroll
    for (int i = 0; i < 4; i++) {
      int c = i * 256 + tid;
      int row = c >> 3;
      int g = ((c & 7) ^ (row & 7)) << 3;
      GLDS(H + (size_t)(m0 + row) * 5120 + k0 + g,
           lA + (size_t)(i * 256 + wid * 64) * 8);
    }
#pragma unroll
    for (int i = 0; i < 2; i++) {
      int c = i * 256 + tid;
      int row = c >> 3;
      int g = ((c & 7) ^ (row & 7)) << 3;
      const unsigned short* gpb;
      if (k0 < 4096) {
        gpb = WdTe + (size_t)(k0 >> 9) * (1024 * 512) +
              (size_t)(n0 + row) * 512 + (k0 & 511) + g;
      } else {
        gpb = WdTs + (size_t)(n0 + row) * 1024 + (k0 - 4096) + g;
      }
      GLDS(gpb, lB + (size_t)(i * 256 + wid * 64) * 8);
    }
    __syncthreads();
    bf16x8 af[4][2], bfr[2][2];
#pragma unroll
    for (int mt = 0; mt < 4; mt++) {
      int row = wm * 64 + mt * 16 + lr;
#pragma unroll
      for (int kt = 0; kt < 2; kt++)
        af[mt][kt] = *(const bf16x8*)(lA + row * 64 +
                                      ((((kt << 2) + quad) ^ (row & 7)) << 3));
    }
#pragma unroll
    for (int nt = 0; nt < 2; nt++) {
      int row = wn * 32 + nt * 16 + lr;
#pragma unroll
      for (int kt = 0; kt < 2; kt++)
        bfr[nt][kt] = *(const bf16x8*)(lB + row * 64 +
                                       ((((kt << 2) + quad) ^ (row & 7)) << 3));
    }
#pragma unroll
    for (int kt = 0; kt < 2; kt++)
#pragma unroll
      for (int mt = 0; mt < 4; mt++)
#pragma unroll
        for (int nt = 0; nt < 2; nt++)
          acc[mt][nt] = __builtin_amdgcn_mfma_f32_16x16x32_bf16(
              af[mt][kt], bfr[nt][kt], acc[mt][nt], 0, 0, 0);
  }

#pragma unroll
  for (int mt = 0; mt < 4; mt++)
#pragma unroll
    for (int nt = 0; nt < 2; nt++)
#pragma unroll
      for (int r = 0; r < 4; r++) {
        int row = m0 + wm * 64 + mt * 16 + quad * 4 + r;
        int col = n0 + wn * 32 + nt * 16 + lr;
        Y[(size_t)row * 1024 + col] = acc[mt][nt][r];
      }
}

extern "C" void kernel_launch(void* const* d_in, const int* in_sizes, int n_in,
                              void* d_out, int out_size, void* d_ws, size_t ws_size,
                              hipStream_t stream) {
  const float* hs  = (const float*)d_in[0];
  const float* rw  = (const float*)d_in[1];
  const float* wg  = (const float*)d_in[2];
  const float* wu  = (const float*)d_in[3];
  const float* wd  = (const float*)d_in[4];
  const float* wsg = (const float*)d_in[5];
  const float* wsu = (const float*)d_in[6];
  const float* wsd = (const float*)d_in[7];
  float* out = (float*)d_out;

  // workspace: cw 128K | Xb 8M | wgT 8M | wuT 8M | wsgT 2M | wsuT 2M |
  //            wdT 8M | wsdT 2M | GH 40/c M.  base = 38.125 MB.
  char* p = (char*)d_ws;
  float* cw = (float*)p;                    p += (size_t)4096 * 8 * 4;
  unsigned short* Xb   = (unsigned short*)p; p += (size_t)4096 * 1024 * 2;
  unsigned short* wgT  = (unsigned short*)p; p += (size_t)8 * 512 * 1024 * 2;
  unsigned short* wuT  = (unsigned short*)p; p += (size_t)8 * 512 * 1024 * 2;
  unsigned short* wsgT = (unsigned short*)p; p += (size_t)1024 * 1024 * 2;
  unsigned short* wsuT = (unsigned short*)p; p += (size_t)1024 * 1024 * 2;
  unsigned short* wdT  = (unsigned short*)p; p += (size_t)8 * 1024 * 512 * 2;
  unsigned short* wsdT = (unsigned short*)p; p += (size_t)1024 * 1024 * 2;
  unsigned short* GH   = (unsigned short*)p;
  const size_t base_bytes = (size_t)(p - (char*)d_ws);

  int chunks = 8;
  for (int c = 1; c <= 8; c *= 2) {
    size_t gh_bytes = ((size_t)4096 / c) * 5120 * 2;
    if (base_bytes + gh_bytes <= ws_size) { chunks = c; break; }
  }
  const int rows = 4096 / chunks;
  const int Mb = rows / 128;

  dim3 tb(32, 8);
  cvt_f32_bf16<<<4096, 256, 0, stream>>>(hs, Xb);
  router_topk<<<4096, 64, 0, stream>>>(hs, rw, cw);
  // routed gate+up transposes fused (z 0..7 gate, 8..15 up)
  transpose_f32_bf16_2<<<dim3(16, 32, 16), tb, 0, stream>>>(
      wg, wgT, 8, wu, wuT, 1024, 512);
  // routed down transpose
  transpose_f32_bf16_2<<<dim3(32, 16, 8), tb, 0, stream>>>(
      wd, wdT, 8, wd, wdT, 512, 1024);
  // shared 3-in-1
  transpose3_1024<<<dim3(32, 32, 3), tb, 0, stream>>>(
      wsg, wsu, wsd, wsgT, wsuT, wsdT);

  for (int c = 0; c < chunks; c++) {
    const unsigned short* Xc = Xb + (size_t)c * rows * 1024;
    const float* cwc = cw + (size_t)c * rows * 8;
    float* outc = out + (size_t)c * rows * 1024;
    gemm_gu_fused<<<Mb * 80, 256, 0, stream>>>(
        Xc, wgT, wsgT, wuT, wsuT, GH, cwc, Mb);
    gemm_down<<<Mb * 16, 256, 0, stream>>>(GH, wdT, wsdT, outc, Mb);
  }
}